// Round 8
// baseline (697.431 us; speedup 1.0000x reference)
//
#include <hip/hip_runtime.h>
#include <hip/hip_bf16.h>
#include <math.h>

#define BB 64
#define CC 256
#define TT 32
#define HH 7
#define WW 7
#define HW 49
#define NN 1568          // T*H*W
#define KV 97
#define KN 300
#define DD 512
#define NTOK 392
#define TOTAL (BB*TT*HW) // 100352
#define BCAP 256         // boundary-bin compaction capacity per head

typedef float f32x4 __attribute__((ext_vector_type(4)));
typedef short bf16x8 __attribute__((ext_vector_type(8)));

#define GLDS(g, l) __builtin_amdgcn_global_load_lds(                          \
    (const __attribute__((address_space(1))) void*)(g),                       \
    (__attribute__((address_space(3))) void*)(l), 16, 0, 0)

// ---------------- K2: wb transpose + per-frame argmax + xp build + CAM rows -
// Blocks 0..2047: one (b,t) frame each — in-block argmax (64-lane shuffle),
// halo'd bf16 xp write, fused CAM row dots. Blocks 2048..6655: wb transpose.
__global__ __launch_bounds__(256) void k_xp(
        const float* __restrict__ x, __hip_bfloat16* __restrict__ xp,
        const float* __restrict__ pv, const float* __restrict__ pn,
        const float* __restrict__ wpv, const float* __restrict__ wpn,
        const float* __restrict__ cw, __hip_bfloat16* __restrict__ wb,
        float* __restrict__ rowv, float* __restrict__ rown_) {
    int blk = blockIdx.x;
    int tid = threadIdx.x;
    if (blk >= 2048) {                  // weight transpose part
        int o = (blk - 2048) * 256 + tid;     // 9*512*256 = 1,179,648
        int kk = o / (DD * CC);
        int rem = o - kk * (DD * CC);
        int d = rem >> 8, c = rem & 255;
        wb[o] = __float2bfloat16(cw[(d * CC + c) * 9 + kk]);
        return;
    }
    __shared__ float xs[CC * HW];       // 50,176 B
    __shared__ float wvs[CC], wns[CC];
    __shared__ float psum[4 * HW];
    __shared__ int cls_sh[2];
    int bt = blk;                       // 0..2047
    int b = bt >> 5, t = bt & 31;
    int lane = tid & 63;

    // in-block argmax: wave 0 -> v head, wave 1 -> n head
    if (tid < 128) {
        int head = tid >> 6;
        const float* r = head ? (pn + b * KN) : (pv + b * KV);
        int K = head ? KN : KV;
        float best = -1e30f; int bi = 0x7fffffff;
        for (int k = lane; k < K; k += 64) {
            float v = r[k];
            if (v > best || (v == best && k < bi)) { best = v; bi = k; }
        }
        #pragma unroll
        for (int off = 32; off >= 1; off >>= 1) {
            float ov = __shfl_xor(best, off);
            int oi = __shfl_xor(bi, off);
            if (ov > best || (ov == best && oi < bi)) { best = ov; bi = oi; }
        }
        if (lane == 0) cls_sh[head] = bi;
    }
    const float* xb = x + ((size_t)b * CC * TT + t) * HW;  // + c*(TT*HW) + q
    for (int i = tid; i < CC * HW; i += 256) {
        int c = i / HW, q = i - (i / HW) * HW;
        xs[i] = xb[(size_t)c * (TT * HW) + q];
    }
    __syncthreads();
    wvs[tid] = wpv[cls_sh[0] * CC + tid];
    wns[tid] = wpn[cls_sh[1] * CC + tid];
    __syncthreads();
    // padded transpose write, 16 B vector stores (8 consecutive c per store)
    __hip_bfloat16* xpb = xp + (size_t)bt * 81 * CC;
    for (int u = tid; u < 81 * 32; u += 256) {
        int p = u >> 5, c0 = (u & 31) * 8;
        int hh = p / 9, ww = p - (p / 9) * 9;
        bool inb = (hh >= 1 && hh <= 7 && ww >= 1 && ww <= 7);
        int base = c0 * HW + (hh - 1) * WW + (ww - 1);
        bf16x8 pack;
        #pragma unroll
        for (int j = 0; j < 8; ++j) {
            float v = inb ? xs[base + j * HW] : 0.f;
            __hip_bfloat16 bv = __float2bfloat16(v);
            pack[j] = *reinterpret_cast<short*>(&bv);
        }
        *reinterpret_cast<bf16x8*>(xpb + p * 256 + c0) = pack;
    }
    // fused CAM rows: 196 threads, half-length dots, then combine
    if (tid < 4 * HW) {
        int sel = tid / HW;             // 0:v-lo 1:v-hi 2:n-lo 3:n-hi
        int q = tid - sel * HW;
        const float* w = (sel < 2) ? wvs : wns;
        int cb2 = (sel & 1) * 128;
        float s = 0.f;
        #pragma unroll 4
        for (int c = 0; c < 128; ++c) s = fmaf(w[cb2 + c], xs[(cb2 + c) * HW + q], s);
        psum[tid] = s;
    }
    __syncthreads();
    if (tid < 2 * HW) {
        int head = tid >= HW;
        int q = head ? tid - HW : tid;
        float s = head ? (psum[2 * HW + q] + psum[3 * HW + q])
                       : (psum[q] + psum[HW + q]);
        (head ? rown_ : rowv)[bt * HW + q] = s;
    }
}

// ---------------- K4: minmax-normalize + top-392 mask + cam_gt --------------
__device__ __forceinline__ int binof(float v) {
    int i = (int)(v * 1024.f);
    return i < 0 ? 0 : (i > 1023 ? 1023 : i);
}

__global__ __launch_bounds__(256) void k_cam(
        const float* __restrict__ rowv, const float* __restrict__ rown_,
        float* __restrict__ cam, int* __restrict__ counter) {
    __shared__ float rv[NN], rn[NN];
    __shared__ float wred[4][4];
    __shared__ int h[1024];             // packed: lo16 = head v, hi16 = head n
    __shared__ int tsum[256];
    __shared__ float lval_v[BCAP], lval_n[BCAP];
    __shared__ int lidx_v[BCAP], lidx_n[BCAP];
    __shared__ int cntv, cntn, bstar_v, above_v, bstar_n, above_n;
    int b = blockIdx.x, tid = threadIdx.x;
    if (b == 0 && tid == 0) *counter = 0;   // k_bce completion counter

    for (int n = tid; n < NN; n += 256) { rv[n] = rowv[b * NN + n]; rn[n] = rown_[b * NN + n]; }
    __syncthreads();
    float mnv = 1e30f, mxv = -1e30f, mnn = 1e30f, mxn = -1e30f;
    for (int n = tid; n < NN; n += 256) {
        float v = rv[n]; mnv = fminf(mnv, v); mxv = fmaxf(mxv, v);
        float u = rn[n]; mnn = fminf(mnn, u); mxn = fmaxf(mxn, u);
    }
    #pragma unroll
    for (int off = 32; off >= 1; off >>= 1) {
        mnv = fminf(mnv, __shfl_xor(mnv, off));
        mxv = fmaxf(mxv, __shfl_xor(mxv, off));
        mnn = fminf(mnn, __shfl_xor(mnn, off));
        mxn = fmaxf(mxn, __shfl_xor(mxn, off));
    }
    if ((tid & 63) == 0) {
        int wid = tid >> 6;
        wred[wid][0] = mnv; wred[wid][1] = mxv; wred[wid][2] = mnn; wred[wid][3] = mxn;
    }
    if (tid == 0) { cntv = 0; cntn = 0; }
    __syncthreads();
    mnv = fminf(fminf(wred[0][0], wred[1][0]), fminf(wred[2][0], wred[3][0]));
    mxv = fmaxf(fmaxf(wred[0][1], wred[1][1]), fmaxf(wred[2][1], wred[3][1]));
    mnn = fminf(fminf(wred[0][2], wred[1][2]), fminf(wred[2][2], wred[3][2]));
    mxn = fmaxf(fmaxf(wred[0][3], wred[1][3]), fmaxf(wred[2][3], wred[3][3]));
    float iv = 1.f / (mxv - mnv), inn = 1.f / (mxn - mnn);

    for (int n = tid; n < NN; n += 256) {
        rv[n] = (rv[n] - mnv) * iv;
        rn[n] = (rn[n] - mnn) * inn;
    }
    for (int i = tid; i < 1024; i += 256) h[i] = 0;
    __syncthreads();
    for (int n = tid; n < NN; n += 256) {
        atomicAdd(&h[binof(rv[n])], 1);
        atomicAdd(&h[binof(rn[n])], 1 << 16);
    }
    __syncthreads();

    int h0 = h[4 * tid], h1 = h[4 * tid + 1], h2 = h[4 * tid + 2], h3 = h[4 * tid + 3];
    tsum[tid] = h0 + h1 + h2 + h3;      // packed fieldwise sum (<=1568 per field)
    __syncthreads();
    for (int off = 1; off < 256; off <<= 1) {
        int add = (tid + off < 256) ? tsum[tid + off] : 0;
        __syncthreads();
        tsum[tid] += add;
        __syncthreads();
    }
    {
        int scur = tsum[tid];           // packed S(4t)
        int hk[4] = {h0, h1, h2, h3};
        #pragma unroll
        for (int k = 0; k < 4; ++k) {
            int snext = scur - hk[k];   // fieldwise, borrow-free
            int sc = scur & 0xffff, nc = snext & 0xffff;
            int sh = scur >> 16, nh = snext >> 16;
            if (sc >= NTOK && nc < NTOK) { bstar_v = 4 * tid + k; above_v = nc; }
            if (sh >= NTOK && nh < NTOK) { bstar_n = 4 * tid + k; above_n = nh; }
            scur = snext;
        }
    }
    __syncthreads();
    int bsv = bstar_v, abv = above_v, bsn = bstar_n, abn = above_n;

    for (int n = tid; n < NN; n += 256) {
        float v = rv[n]; int bv = binof(v);
        if (bv < bsv) rv[n] = 0.f;
        else if (bv == bsv) {
            int s = atomicAdd(&cntv, 1);
            if (s < BCAP) { lval_v[s] = v; lidx_v[s] = n; }
        }
        float u = rn[n]; int bu = binof(u);
        if (bu < bsn) rn[n] = 0.f;
        else if (bu == bsn) {
            int s = atomicAdd(&cntn, 1);
            if (s < BCAP) { lval_n[s] = u; lidx_n[s] = n; }
        }
    }
    __syncthreads();
    int Lv = cntv < BCAP ? cntv : BCAP;
    int Ln = cntn < BCAP ? cntn : BCAP;
    for (int i = tid; i < Lv; i += 256) {
        float vi = lval_v[i]; int ni = lidx_v[i]; int r = 0;
        for (int j = 0; j < Lv; ++j) {
            float vj = lval_v[j]; int nj = lidx_v[j];
            r += (vj > vi || (vj == vi && nj < ni)) ? 1 : 0;
        }
        rv[ni] = (r < NTOK - abv) ? vi : 0.f;
    }
    for (int i = tid; i < Ln; i += 256) {
        float vi = lval_n[i]; int ni = lidx_n[i]; int r = 0;
        for (int j = 0; j < Ln; ++j) {
            float vj = lval_n[j]; int nj = lidx_n[j];
            r += (vj > vi || (vj == vi && nj < ni)) ? 1 : 0;
        }
        rn[ni] = (r < NTOK - abn) ? vi : 0.f;
    }
    __syncthreads();
    for (int n = tid; n < NN; n += 256) cam[b * NN + n] = fmaxf(rv[n], rn[n]);
}

// ---------------- K5: MFMA implicit-GEMM conv + fused relu/score ------------
// 128x128 tile (R6-verified) with B read DIRECTLY from global (L2-resident,
// 2.36 MB/XCD): halves ds_read traffic and GLDS staging vs R6 — LDS pipe
// (R6 limiter at ~80% busy) drops below the MFMA floor. A stays via
// swizzled GLDS (HBM-once, L2-shared among the 4 nblk blocks per mtile).
__global__ __launch_bounds__(256, 3) void k_gemm(
        const __hip_bfloat16* __restrict__ xp, const __hip_bfloat16* __restrict__ wb,
        const float* __restrict__ convb, const float* __restrict__ scorew,
        float* __restrict__ pl) {
    __shared__ char As[16384];   // [row 0..127][seg 0..7] bf16x8, xor-swizzled
    int tid = threadIdx.x;
    int bid = blockIdx.x;        // 0..3135
    int xcd = bid & 7;
    int local = bid >> 3;        // 0..391
    int mtile = xcd * 98 + (local >> 2);
    int nblk = local & 3;
    int m0 = mtile * 128;
    int n0 = nblk * 128;
    int lane = tid & 63, wv = tid >> 6;
    int wm = wv >> 1, wn = wv & 1;
    int ln = lane & 15, qd = lane >> 4;

    // A staging coords (lane owns LDS slot row=tid>>3, seg=tid&7; stages
    // global segment seg^(row&7) -> physical xor-swizzle, conflict-free)
    int rrow = tid >> 3;
    int segst = ((tid & 7) ^ (rrow & 7)) * 8;
    int bt_[4], hh_[4], ww_[4];
    #pragma unroll
    for (int j = 0; j < 4; ++j) {
        int m = m0 + j * 32 + rrow;
        int bt = m / HW, q = m - bt * HW;
        bt_[j] = bt; hh_[j] = q / WW; ww_[j] = q - (q / WW) * WW;
    }
    // B fragment base pointers (direct global): row n0+wn*64+j*16+ln, +qd*8
    const __hip_bfloat16* bfrp[4];
    #pragma unroll
    for (int j = 0; j < 4; ++j)
        bfrp[j] = wb + (size_t)(n0 + wn * 64 + j * 16 + ln) * 256 + qd * 8;

    int swz = ln & 7;
    int offk[2] = {((0 + qd) ^ swz) * 16, ((4 + qd) ^ swz) * 16};

    f32x4 acc[4][4];
    #pragma unroll
    for (int i = 0; i < 4; ++i)
        #pragma unroll
        for (int j = 0; j < 4; ++j) acc[i][j] = (f32x4){0.f, 0.f, 0.f, 0.f};

    for (int kk = 0; kk < 9; ++kk) {
        int kh = kk / 3, kw = kk - (kk / 3) * 3;
        const __hip_bfloat16* aptr[4];
        #pragma unroll
        for (int j = 0; j < 4; ++j)
            aptr[j] = xp + ((size_t)bt_[j] * 81 + (hh_[j] + kh) * 9 + (ww_[j] + kw)) * 256 + segst;
        const size_t boff = (size_t)kk * (DD * 256);
        #pragma unroll
        for (int c0 = 0; c0 < 256; c0 += 64) {
            __syncthreads();
            #pragma unroll
            for (int j = 0; j < 4; ++j)
                GLDS(aptr[j] + c0, As + j * 4096 + tid * 16);
            // B fragments: direct global loads (L2-hit), drain with barrier
            bf16x8 bfr[2][4];
            #pragma unroll
            for (int k2 = 0; k2 < 2; ++k2)
                #pragma unroll
                for (int j = 0; j < 4; ++j)
                    bfr[k2][j] = *(const bf16x8*)(bfrp[j] + boff + c0 + k2 * 32);
            __syncthreads();
            #pragma unroll
            for (int k2 = 0; k2 < 2; ++k2) {
                bf16x8 af[4];
                #pragma unroll
                for (int i = 0; i < 4; ++i)
                    af[i] = *(const bf16x8*)(As + (wm * 64 + i * 16 + ln) * 128 + offk[k2]);
                #pragma unroll
                for (int i = 0; i < 4; ++i)
                    #pragma unroll
                    for (int j = 0; j < 4; ++j)
                        acc[i][j] = __builtin_amdgcn_mfma_f32_16x16x32_bf16(af[i], bfr[k2][j], acc[i][j], 0, 0, 0);
            }
        }
    }

    float swr[4], cbr[4];
    #pragma unroll
    for (int j = 0; j < 4; ++j) {
        int n = n0 + wn * 64 + j * 16 + ln;
        swr[j] = scorew[n];
        cbr[j] = convb[n];
    }
    float* dst = pl + (size_t)(nblk * 2 + wn) * TOTAL;
    #pragma unroll
    for (int i = 0; i < 4; ++i) {
        #pragma unroll
        for (int r = 0; r < 4; ++r) {
            float v = 0.f;
            #pragma unroll
            for (int j = 0; j < 4; ++j) {
                float h1 = acc[i][j][r] + cbr[j];
                h1 = h1 > 0.f ? h1 : 0.f;
                v = fmaf(swr[j], h1, v);
            }
            v += __shfl_xor(v, 1);
            v += __shfl_xor(v, 2);
            v += __shfl_xor(v, 4);
            v += __shfl_xor(v, 8);
            if (ln == 0)
                dst[m0 + wm * 64 + i * 16 + qd * 4 + r] = v;
        }
    }
}

// ---------------- K6: slot-sum + BCE + grid reduction (last block) ----------
__global__ __launch_bounds__(256) void k_bce(
        const float* __restrict__ pl, const float* __restrict__ cam,
        const float* __restrict__ sb, float* __restrict__ part,
        int* __restrict__ counter, float* __restrict__ out) {
    __shared__ float sbuf[256];
    __shared__ int isLast;
    int tid = threadIdx.x;
    int m = blockIdx.x * 256 + tid;
    float l = sb[0];
    #pragma unroll
    for (int s = 0; s < 8; ++s) l += pl[(size_t)s * TOTAL + m];
    float y = cam[m];
    float v = fmaxf(l, 0.f) - l * y + log1pf(expf(-fabsf(l)));
    sbuf[tid] = v; __syncthreads();
    for (int k = 128; k > 0; k >>= 1) {
        if (tid < k) sbuf[tid] += sbuf[tid + k];
        __syncthreads();
    }
    if (tid == 0) {
        part[blockIdx.x] = sbuf[0];
        __threadfence();
        int d = atomicAdd(counter, 1);
        isLast = (d == 391);
    }
    __syncthreads();
    if (isLast) {
        float s = 0.f;
        for (int i = tid; i < 392; i += 256) s += part[i];
        sbuf[tid] = s; __syncthreads();
        for (int k = 128; k > 0; k >>= 1) {
            if (tid < k) sbuf[tid] += sbuf[tid + k];
            __syncthreads();
        }
        if (tid == 0) out[0] = sbuf[0] * (1.0f / (float)TOTAL);
    }
}

extern "C" void kernel_launch(void* const* d_in, const int* in_sizes, int n_in,
                              void* d_out, int out_size, void* d_ws, size_t ws_size,
                              hipStream_t stream) {
    const float* x   = (const float*)d_in[0];
    const float* pv  = (const float*)d_in[1];
    const float* pn  = (const float*)d_in[2];
    const float* wpv = (const float*)d_in[3];
    const float* wpn = (const float*)d_in[4];
    const float* cw  = (const float*)d_in[5];
    const float* cb  = (const float*)d_in[6];
    const float* sw  = (const float*)d_in[7];
    const float* sb  = (const float*)d_in[8];

    char* w8 = (char*)d_ws;
    __hip_bfloat16* xp  = (__hip_bfloat16*)w8;                  // 84,934,656 B
    __hip_bfloat16* wb  = (__hip_bfloat16*)(w8 + 84934656);     //  2,359,296 B
    float* pl      = (float*)(w8 + 87293952);                   //  3,211,264 B
    float* rowv    = (float*)(w8 + 90505216);                   //    401,408 B
    float* rown_   = (float*)(w8 + 90906624);                   //    401,408 B
    float* cam     = (float*)(w8 + 91308032);                   //    401,408 B
    float* part    = (float*)(w8 + 91709440);                   //      1,568 B
    int*   counter = (int*)(w8 + 91711008);                     //          4 B

    k_xp<<<2048 + 4608, 256, 0, stream>>>(x, xp, pv, pn, wpv, wpn, cw, wb, rowv, rown_);
    k_cam<<<BB, 256, 0, stream>>>(rowv, rown_, cam, counter);
    k_gemm<<<3136, 256, 0, stream>>>(xp, wb, cb, sw, pl);
    k_bce<<<392, 256, 0, stream>>>(pl, cam, sb, part, counter, (float*)d_out);
}

// Round 9
// 447.028 us; speedup vs baseline: 1.5602x; 1.5602x over previous
//
#include <hip/hip_runtime.h>
#include <hip/hip_bf16.h>
#include <math.h>

#define BB 64
#define CC 256
#define TT 32
#define HH 7
#define WW 7
#define HW 49
#define NN 1568          // T*H*W
#define KV 97
#define KN 300
#define DD 512
#define NTOK 392
#define TOTAL (BB*TT*HW) // 100352
#define BCAP 256         // boundary-bin compaction capacity per head

typedef float f32x4 __attribute__((ext_vector_type(4)));
typedef short bf16x8 __attribute__((ext_vector_type(8)));

#define GLDS(g, l) __builtin_amdgcn_global_load_lds(                          \
    (const __attribute__((address_space(1))) void*)(g),                       \
    (__attribute__((address_space(3))) void*)(l), 16, 0, 0)

// ---------------- K2: wb transpose + per-frame argmax + xp build + CAM rows -
// Blocks 0..2047: one (b,t) frame each — in-block argmax (64-lane shuffle),
// halo'd bf16 xp write, fused CAM row dots. Blocks 2048..6655: wb transpose.
__global__ __launch_bounds__(256) void k_xp(
        const float* __restrict__ x, __hip_bfloat16* __restrict__ xp,
        const float* __restrict__ pv, const float* __restrict__ pn,
        const float* __restrict__ wpv, const float* __restrict__ wpn,
        const float* __restrict__ cw, __hip_bfloat16* __restrict__ wb,
        float* __restrict__ rowv, float* __restrict__ rown_,
        int* __restrict__ counter) {
    int blk = blockIdx.x;
    int tid = threadIdx.x;
    if (blk >= 2048) {                  // weight transpose part
        if (blk == 2048 && tid == 0) *counter = 0;   // k_bce completion counter
        int o = (blk - 2048) * 256 + tid;     // 9*512*256 = 1,179,648
        int kk = o / (DD * CC);
        int rem = o - kk * (DD * CC);
        int d = rem >> 8, c = rem & 255;
        wb[o] = __float2bfloat16(cw[(d * CC + c) * 9 + kk]);
        return;
    }
    __shared__ float xs[CC * HW];       // 50,176 B
    __shared__ float wvs[CC], wns[CC];
    __shared__ float psum[4 * HW];
    __shared__ int cls_sh[2];
    int bt = blk;                       // 0..2047
    int b = bt >> 5, t = bt & 31;
    int lane = tid & 63;

    // in-block argmax: wave 0 -> v head, wave 1 -> n head
    if (tid < 128) {
        int head = tid >> 6;
        const float* r = head ? (pn + b * KN) : (pv + b * KV);
        int K = head ? KN : KV;
        float best = -1e30f; int bi = 0x7fffffff;
        for (int k = lane; k < K; k += 64) {
            float v = r[k];
            if (v > best || (v == best && k < bi)) { best = v; bi = k; }
        }
        #pragma unroll
        for (int off = 32; off >= 1; off >>= 1) {
            float ov = __shfl_xor(best, off);
            int oi = __shfl_xor(bi, off);
            if (ov > best || (ov == best && oi < bi)) { best = ov; bi = oi; }
        }
        if (lane == 0) cls_sh[head] = bi;
    }
    const float* xb = x + ((size_t)b * CC * TT + t) * HW;  // + c*(TT*HW) + q
    for (int i = tid; i < CC * HW; i += 256) {
        int c = i / HW, q = i - (i / HW) * HW;
        xs[i] = xb[(size_t)c * (TT * HW) + q];
    }
    __syncthreads();
    wvs[tid] = wpv[cls_sh[0] * CC + tid];
    wns[tid] = wpn[cls_sh[1] * CC + tid];
    __syncthreads();
    // padded transpose write, 16 B vector stores (8 consecutive c per store)
    __hip_bfloat16* xpb = xp + (size_t)bt * 81 * CC;
    for (int u = tid; u < 81 * 32; u += 256) {
        int p = u >> 5, c0 = (u & 31) * 8;
        int hh = p / 9, ww = p - (p / 9) * 9;
        bool inb = (hh >= 1 && hh <= 7 && ww >= 1 && ww <= 7);
        int base = c0 * HW + (hh - 1) * WW + (ww - 1);
        bf16x8 pack;
        #pragma unroll
        for (int j = 0; j < 8; ++j) {
            float v = inb ? xs[base + j * HW] : 0.f;
            __hip_bfloat16 bv = __float2bfloat16(v);
            pack[j] = *reinterpret_cast<short*>(&bv);
        }
        *reinterpret_cast<bf16x8*>(xpb + p * 256 + c0) = pack;
    }
    // fused CAM rows: 196 threads, half-length dots, then combine
    if (tid < 4 * HW) {
        int sel = tid / HW;             // 0:v-lo 1:v-hi 2:n-lo 3:n-hi
        int q = tid - sel * HW;
        const float* w = (sel < 2) ? wvs : wns;
        int cb2 = (sel & 1) * 128;
        float s = 0.f;
        #pragma unroll 4
        for (int c = 0; c < 128; ++c) s = fmaf(w[cb2 + c], xs[(cb2 + c) * HW + q], s);
        psum[tid] = s;
    }
    __syncthreads();
    if (tid < 2 * HW) {
        int head = tid >= HW;
        int q = head ? tid - HW : tid;
        float s = head ? (psum[2 * HW + q] + psum[3 * HW + q])
                       : (psum[q] + psum[HW + q]);
        (head ? rown_ : rowv)[bt * HW + q] = s;
    }
}

// ---------------- cam selection (runs as blocks 0..63 of k_gemm) ------------
__device__ __forceinline__ int binof(float v) {
    int i = (int)(v * 1024.f);
    return i < 0 ? 0 : (i > 1023 ? 1023 : i);
}

__device__ void cam_block(int b, int tid, char* smem,
                          const float* __restrict__ rowv,
                          const float* __restrict__ rown_,
                          float* __restrict__ cam) {
    float* rv = (float*)smem;                 // 6272 B
    float* rn = (float*)(smem + 6272);        // 6272 B
    int* h = (int*)(smem + 12544);            // 4096 B, packed lo16 v / hi16 n
    int* tsum = (int*)(smem + 16640);         // 1024 B
    float* lval_v = (float*)(smem + 17664);   // 1024 B
    int* lidx_v = (int*)(smem + 18688);       // 1024 B
    float* lval_n = (float*)(smem + 19712);   // 1024 B
    int* lidx_n = (int*)(smem + 20736);       // 1024 B
    float* wred = (float*)(smem + 21760);     // 64 B  [wave][4]
    int* sc = (int*)(smem + 21824);           // 6 ints: cntv cntn bsv abv bsn abn

    for (int n = tid; n < NN; n += 256) { rv[n] = rowv[b * NN + n]; rn[n] = rown_[b * NN + n]; }
    __syncthreads();
    float mnv = 1e30f, mxv = -1e30f, mnn = 1e30f, mxn = -1e30f;
    for (int n = tid; n < NN; n += 256) {
        float v = rv[n]; mnv = fminf(mnv, v); mxv = fmaxf(mxv, v);
        float u = rn[n]; mnn = fminf(mnn, u); mxn = fmaxf(mxn, u);
    }
    #pragma unroll
    for (int off = 32; off >= 1; off >>= 1) {
        mnv = fminf(mnv, __shfl_xor(mnv, off));
        mxv = fmaxf(mxv, __shfl_xor(mxv, off));
        mnn = fminf(mnn, __shfl_xor(mnn, off));
        mxn = fmaxf(mxn, __shfl_xor(mxn, off));
    }
    if ((tid & 63) == 0) {
        int wid = tid >> 6;
        wred[wid * 4 + 0] = mnv; wred[wid * 4 + 1] = mxv;
        wred[wid * 4 + 2] = mnn; wred[wid * 4 + 3] = mxn;
    }
    if (tid == 0) { sc[0] = 0; sc[1] = 0; }
    __syncthreads();
    mnv = fminf(fminf(wred[0], wred[4]), fminf(wred[8], wred[12]));
    mxv = fmaxf(fmaxf(wred[1], wred[5]), fmaxf(wred[9], wred[13]));
    mnn = fminf(fminf(wred[2], wred[6]), fminf(wred[10], wred[14]));
    mxn = fmaxf(fmaxf(wred[3], wred[7]), fmaxf(wred[11], wred[15]));
    float iv = 1.f / (mxv - mnv), inn = 1.f / (mxn - mnn);

    for (int n = tid; n < NN; n += 256) {
        rv[n] = (rv[n] - mnv) * iv;
        rn[n] = (rn[n] - mnn) * inn;
    }
    for (int i = tid; i < 1024; i += 256) h[i] = 0;
    __syncthreads();
    for (int n = tid; n < NN; n += 256) {
        atomicAdd(&h[binof(rv[n])], 1);
        atomicAdd(&h[binof(rn[n])], 1 << 16);
    }
    __syncthreads();

    int h0 = h[4 * tid], h1 = h[4 * tid + 1], h2 = h[4 * tid + 2], h3 = h[4 * tid + 3];
    tsum[tid] = h0 + h1 + h2 + h3;      // packed fieldwise sum (<=1568 per field)
    __syncthreads();
    for (int off = 1; off < 256; off <<= 1) {
        int add = (tid + off < 256) ? tsum[tid + off] : 0;
        __syncthreads();
        tsum[tid] += add;
        __syncthreads();
    }
    {
        int scur = tsum[tid];           // packed S(4t)
        int hk[4] = {h0, h1, h2, h3};
        #pragma unroll
        for (int k = 0; k < 4; ++k) {
            int snext = scur - hk[k];   // fieldwise, borrow-free
            int scv = scur & 0xffff, ncv = snext & 0xffff;
            int sh = scur >> 16, nh = snext >> 16;
            if (scv >= NTOK && ncv < NTOK) { sc[2] = 4 * tid + k; sc[3] = ncv; }
            if (sh >= NTOK && nh < NTOK) { sc[4] = 4 * tid + k; sc[5] = nh; }
            scur = snext;
        }
    }
    __syncthreads();
    int bsv = sc[2], abv = sc[3], bsn = sc[4], abn = sc[5];

    for (int n = tid; n < NN; n += 256) {
        float v = rv[n]; int bv = binof(v);
        if (bv < bsv) rv[n] = 0.f;
        else if (bv == bsv) {
            int s = atomicAdd(&sc[0], 1);
            if (s < BCAP) { lval_v[s] = v; lidx_v[s] = n; }
        }
        float u = rn[n]; int bu = binof(u);
        if (bu < bsn) rn[n] = 0.f;
        else if (bu == bsn) {
            int s = atomicAdd(&sc[1], 1);
            if (s < BCAP) { lval_n[s] = u; lidx_n[s] = n; }
        }
    }
    __syncthreads();
    int Lv = sc[0] < BCAP ? sc[0] : BCAP;
    int Ln = sc[1] < BCAP ? sc[1] : BCAP;
    for (int i = tid; i < Lv; i += 256) {
        float vi = lval_v[i]; int ni = lidx_v[i]; int r = 0;
        for (int j = 0; j < Lv; ++j) {
            float vj = lval_v[j]; int nj = lidx_v[j];
            r += (vj > vi || (vj == vi && nj < ni)) ? 1 : 0;
        }
        rv[ni] = (r < NTOK - abv) ? vi : 0.f;
    }
    for (int i = tid; i < Ln; i += 256) {
        float vi = lval_n[i]; int ni = lidx_n[i]; int r = 0;
        for (int j = 0; j < Ln; ++j) {
            float vj = lval_n[j]; int nj = lidx_n[j];
            r += (vj > vi || (vj == vi && nj < ni)) ? 1 : 0;
        }
        rn[ni] = (r < NTOK - abn) ? vi : 0.f;
    }
    __syncthreads();
    for (int n = tid; n < NN; n += 256) cam[b * NN + n] = fmaxf(rv[n], rn[n]);
}

// ---------------- K5: MFMA implicit-GEMM conv + fused relu/score + cam ------
// R6-verified GEMM core (B staged in LDS, xor-swizzle, XCD remap, slot
// stores). Blocks 0..63 run the cam selection (hides under the GEMM);
// blocks 64..3199 are the GEMM (gid = bid-64; 64%8==0 keeps XCD map).
__global__ __launch_bounds__(256, 3) void k_gemm(
        const __hip_bfloat16* __restrict__ xp, const __hip_bfloat16* __restrict__ wb,
        const float* __restrict__ convb, const float* __restrict__ scorew,
        float* __restrict__ pl, const float* __restrict__ rowv,
        const float* __restrict__ rown_, float* __restrict__ cam) {
    __shared__ char smem[32768];
    int tid = threadIdx.x;
    int bid = blockIdx.x;        // 0..3199
    if (bid < 64) { cam_block(bid, tid, smem, rowv, rown_, cam); return; }
    char* As = smem;             // [row 0..127][seg 0..7] bf16x8, swizzled
    char* Bs = smem + 16384;     // [d'  0..127][seg 0..7]
    int gid = bid - 64;          // 0..3135
    int xcd = gid & 7;
    int local = gid >> 3;        // 0..391
    int mtile = xcd * 98 + (local >> 2);
    int nblk = local & 3;
    int m0 = mtile * 128;
    int n0 = nblk * 128;
    int lane = tid & 63, wv = tid >> 6;
    int wm = wv >> 1, wn = wv & 1;
    int ln = lane & 15, qd = lane >> 4;

    int rrow = tid >> 3;
    int segst = ((tid & 7) ^ (rrow & 7)) * 8;     // element offset in row
    int bt_[4], hh_[4], ww_[4];
    const __hip_bfloat16* bptr[4];
    #pragma unroll
    for (int j = 0; j < 4; ++j) {
        int m = m0 + j * 32 + rrow;
        int bt = m / HW, q = m - bt * HW;
        bt_[j] = bt; hh_[j] = q / WW; ww_[j] = q - (q / WW) * WW;
        bptr[j] = wb + (size_t)(n0 + j * 32 + rrow) * 256 + segst;
    }

    int swz = ln & 7;
    int offk[2] = {((0 + qd) ^ swz) * 16, ((4 + qd) ^ swz) * 16};

    f32x4 acc[4][4];
    #pragma unroll
    for (int i = 0; i < 4; ++i)
        #pragma unroll
        for (int j = 0; j < 4; ++j) acc[i][j] = (f32x4){0.f, 0.f, 0.f, 0.f};

    for (int kk = 0; kk < 9; ++kk) {
        int kh = kk / 3, kw = kk - (kk / 3) * 3;
        const __hip_bfloat16* aptr[4];
        #pragma unroll
        for (int j = 0; j < 4; ++j)
            aptr[j] = xp + ((size_t)bt_[j] * 81 + (hh_[j] + kh) * 9 + (ww_[j] + kw)) * 256 + segst;
        const size_t boff = (size_t)kk * (DD * 256);
        #pragma unroll
        for (int c0 = 0; c0 < 256; c0 += 64) {
            __syncthreads();
            #pragma unroll
            for (int j = 0; j < 4; ++j) {
                GLDS(aptr[j] + c0, As + j * 4096 + tid * 16);
                GLDS(bptr[j] + boff + c0, Bs + j * 4096 + tid * 16);
            }
            __syncthreads();
            #pragma unroll
            for (int k2 = 0; k2 < 2; ++k2) {
                bf16x8 af[4], bfr[4];
                #pragma unroll
                for (int i = 0; i < 4; ++i)
                    af[i] = *(const bf16x8*)(As + (wm * 64 + i * 16 + ln) * 128 + offk[k2]);
                #pragma unroll
                for (int j = 0; j < 4; ++j)
                    bfr[j] = *(const bf16x8*)(Bs + (wn * 64 + j * 16 + ln) * 128 + offk[k2]);
                #pragma unroll
                for (int i = 0; i < 4; ++i)
                    #pragma unroll
                    for (int j = 0; j < 4; ++j)
                        acc[i][j] = __builtin_amdgcn_mfma_f32_16x16x32_bf16(af[i], bfr[j], acc[i][j], 0, 0, 0);
            }
        }
    }

    float swr[4], cbr[4];
    #pragma unroll
    for (int j = 0; j < 4; ++j) {
        int n = n0 + wn * 64 + j * 16 + ln;
        swr[j] = scorew[n];
        cbr[j] = convb[n];
    }
    float* dst = pl + (size_t)(nblk * 2 + wn) * TOTAL;
    #pragma unroll
    for (int i = 0; i < 4; ++i) {
        #pragma unroll
        for (int r = 0; r < 4; ++r) {
            float v = 0.f;
            #pragma unroll
            for (int j = 0; j < 4; ++j) {
                float h1 = acc[i][j][r] + cbr[j];
                h1 = h1 > 0.f ? h1 : 0.f;
                v = fmaf(swr[j], h1, v);
            }
            v += __shfl_xor(v, 1);
            v += __shfl_xor(v, 2);
            v += __shfl_xor(v, 4);
            v += __shfl_xor(v, 8);
            if (ln == 0)
                dst[m0 + wm * 64 + i * 16 + qd * 4 + r] = v;
        }
    }
}

// ---------------- K6: slot-sum + BCE + grid reduction (last block) ----------
__global__ __launch_bounds__(256) void k_bce(
        const float* __restrict__ pl, const float* __restrict__ cam,
        const float* __restrict__ sb, float* __restrict__ part,
        int* __restrict__ counter, float* __restrict__ out) {
    __shared__ float sbuf[256];
    __shared__ int isLast;
    int tid = threadIdx.x;
    int m = blockIdx.x * 256 + tid;
    float l = sb[0];
    #pragma unroll
    for (int s = 0; s < 8; ++s) l += pl[(size_t)s * TOTAL + m];
    float y = cam[m];
    float v = fmaxf(l, 0.f) - l * y + log1pf(expf(-fabsf(l)));
    sbuf[tid] = v; __syncthreads();
    for (int k = 128; k > 0; k >>= 1) {
        if (tid < k) sbuf[tid] += sbuf[tid + k];
        __syncthreads();
    }
    if (tid == 0) {
        part[blockIdx.x] = sbuf[0];
        __threadfence();
        int d = atomicAdd(counter, 1);
        isLast = (d == 391);
    }
    __syncthreads();
    if (isLast) {
        float s = 0.f;
        for (int i = tid; i < 392; i += 256) s += part[i];
        sbuf[tid] = s; __syncthreads();
        for (int k = 128; k > 0; k >>= 1) {
            if (tid < k) sbuf[tid] += sbuf[tid + k];
            __syncthreads();
        }
        if (tid == 0) out[0] = sbuf[0] * (1.0f / (float)TOTAL);
    }
}

extern "C" void kernel_launch(void* const* d_in, const int* in_sizes, int n_in,
                              void* d_out, int out_size, void* d_ws, size_t ws_size,
                              hipStream_t stream) {
    const float* x   = (const float*)d_in[0];
    const float* pv  = (const float*)d_in[1];
    const float* pn  = (const float*)d_in[2];
    const float* wpv = (const float*)d_in[3];
    const float* wpn = (const float*)d_in[4];
    const float* cw  = (const float*)d_in[5];
    const float* cb  = (const float*)d_in[6];
    const float* sw  = (const float*)d_in[7];
    const float* sb  = (const float*)d_in[8];

    char* w8 = (char*)d_ws;
    __hip_bfloat16* xp  = (__hip_bfloat16*)w8;                  // 84,934,656 B
    __hip_bfloat16* wb  = (__hip_bfloat16*)(w8 + 84934656);     //  2,359,296 B
    float* pl      = (float*)(w8 + 87293952);                   //  3,211,264 B
    float* rowv    = (float*)(w8 + 90505216);                   //    401,408 B
    float* rown_   = (float*)(w8 + 90906624);                   //    401,408 B
    float* cam     = (float*)(w8 + 91308032);                   //    401,408 B
    float* part    = (float*)(w8 + 91709440);                   //      1,568 B
    int*   counter = (int*)(w8 + 91711008);                     //          4 B

    k_xp<<<2048 + 4608, 256, 0, stream>>>(x, xp, pv, pn, wpv, wpn, cw, wb,
                                          rowv, rown_, counter);
    k_gemm<<<64 + 3136, 256, 0, stream>>>(xp, wb, cb, sw, pl, rowv, rown_, cam);
    k_bce<<<392, 256, 0, stream>>>(pl, cam, sb, part, counter, (float*)d_out);
}

// Round 10
// 437.181 us; speedup vs baseline: 1.5953x; 1.0225x over previous
//
#include <hip/hip_runtime.h>
#include <hip/hip_bf16.h>
#include <math.h>

#define BB 64
#define CC 256
#define TT 32
#define HH 7
#define WW 7
#define HW 49
#define NN 1568          // T*H*W
#define KV 97
#define KN 300
#define DD 512
#define NTOK 392
#define TOTAL (BB*TT*HW) // 100352
#define BCAP 256         // boundary-bin compaction capacity per head
#define XP_P 257         // odd LDS pitch for the transposed frame stage

typedef float f32x4 __attribute__((ext_vector_type(4)));
typedef short bf16x8 __attribute__((ext_vector_type(8)));

#define GLDS(g, l) __builtin_amdgcn_global_load_lds(                          \
    (const __attribute__((address_space(1))) void*)(g),                       \
    (__attribute__((address_space(3))) void*)(l), 16, 0, 0)

// ---------------- K2: per-frame argmax + xp build + CAM rows + wb slice -----
// 2048 blocks, one (b,t) frame each. LDS stage is TRANSPOSED: xs2[q*257+c]
// (odd pitch): phase-1 writes lane-stride 257 -> conflict-free; transpose-
// pack reads 8 contiguous floats (4-way, 1.58x); CAM dot lane-stride 257 ->
// conflict-free. Each block also transposes its 576-elem slice of wb.
__global__ __launch_bounds__(256) void k_xp(
        const float* __restrict__ x, __hip_bfloat16* __restrict__ xp,
        const float* __restrict__ pv, const float* __restrict__ pn,
        const float* __restrict__ wpv, const float* __restrict__ wpn,
        const float* __restrict__ cw, __hip_bfloat16* __restrict__ wb,
        float* __restrict__ rowv, float* __restrict__ rown_,
        int* __restrict__ counter) {
    __shared__ float xs2[HW * XP_P + 7];    // 50,400 B
    __shared__ float wvs[CC], wns[CC];
    __shared__ float psum[4 * HW];
    __shared__ int cls_sh[2];
    int bt = blockIdx.x;                // 0..2047
    int tid = threadIdx.x;
    int b = bt >> 5, t = bt & 31;
    int lane = tid & 63;
    if (bt == 0 && tid == 0) *counter = 0;   // k_bce completion counter

    // wb slice: elements [bt*576, bt*576+576)  (stride-9 gather, tiny)
    {
        int base = bt * 576;
        #pragma unroll
        for (int r = 0; r < 3; ++r) {
            int o = base + r * 256 + tid;
            if (o < base + 576) {
                int kk = o / (DD * CC);
                int rem = o - kk * (DD * CC);
                int d = rem >> 8, c = rem & 255;
                wb[o] = __float2bfloat16(cw[(d * CC + c) * 9 + kk]);
            }
        }
    }

    // in-block argmax: wave 0 -> v head, wave 1 -> n head
    if (tid < 128) {
        int head = tid >> 6;
        const float* r = head ? (pn + b * KN) : (pv + b * KV);
        int K = head ? KN : KV;
        float best = -1e30f; int bi = 0x7fffffff;
        for (int k = lane; k < K; k += 64) {
            float v = r[k];
            if (v > best || (v == best && k < bi)) { best = v; bi = k; }
        }
        #pragma unroll
        for (int off = 32; off >= 1; off >>= 1) {
            float ov = __shfl_xor(best, off);
            int oi = __shfl_xor(bi, off);
            if (ov > best || (ov == best && oi < bi)) { best = ov; bi = oi; }
        }
        if (lane == 0) cls_sh[head] = bi;
    }

    // phase 1: coalesced global read, transposed LDS write (conflict-free)
    const float* xb = x + ((size_t)b * CC * TT + t) * HW;  // + c*(TT*HW) + q
    for (int i = tid; i < CC * HW; i += 256) {
        int c = i / HW, q = i - (i / HW) * HW;
        xs2[q * XP_P + c] = xb[(size_t)c * (TT * HW) + q];
    }
    __syncthreads();
    wvs[tid] = wpv[cls_sh[0] * CC + tid];
    wns[tid] = wpn[cls_sh[1] * CC + tid];
    __syncthreads();

    // transpose-pack: 8 contiguous LDS floats -> bf16x8 -> coalesced 16B store
    __hip_bfloat16* xpb = xp + (size_t)bt * 81 * CC;
    for (int u = tid; u < 81 * 32; u += 256) {
        int p = u >> 5, c0 = (u & 31) * 8;
        int hh = p / 9, ww = p - (p / 9) * 9;
        bool inb = (hh >= 1 && hh <= 7 && ww >= 1 && ww <= 7);
        const float* row = xs2 + ((hh - 1) * 7 + (ww - 1)) * XP_P + c0;
        bf16x8 pack;
        #pragma unroll
        for (int j = 0; j < 8; ++j) {
            float v = inb ? row[j] : 0.f;
            __hip_bfloat16 bv = __float2bfloat16(v);
            pack[j] = *reinterpret_cast<short*>(&bv);
        }
        *reinterpret_cast<bf16x8*>(xpb + p * 256 + c0) = pack;
    }

    // fused CAM rows: 196 threads, half-length dots, then combine
    if (tid < 4 * HW) {
        int sel = tid / HW;             // 0:v-lo 1:v-hi 2:n-lo 3:n-hi
        int q = tid - sel * HW;
        const float* w = (sel < 2) ? wvs : wns;
        int cb2 = (sel & 1) * 128;
        const float* row = xs2 + q * XP_P + cb2;
        float s = 0.f;
        #pragma unroll 4
        for (int c = 0; c < 128; ++c) s = fmaf(w[cb2 + c], row[c], s);
        psum[tid] = s;
    }
    __syncthreads();
    if (tid < 2 * HW) {
        int head = tid >= HW;
        int q = head ? tid - HW : tid;
        float s = head ? (psum[2 * HW + q] + psum[3 * HW + q])
                       : (psum[q] + psum[HW + q]);
        (head ? rown_ : rowv)[bt * HW + q] = s;
    }
}

// ---------------- cam selection (runs as blocks 0..63 of k_gemm) ------------
__device__ __forceinline__ int binof(float v) {
    int i = (int)(v * 1024.f);
    return i < 0 ? 0 : (i > 1023 ? 1023 : i);
}

__device__ void cam_block(int b, int tid, char* smem,
                          const float* __restrict__ rowv,
                          const float* __restrict__ rown_,
                          float* __restrict__ cam) {
    float* rv = (float*)smem;                 // 6272 B
    float* rn = (float*)(smem + 6272);        // 6272 B
    int* h = (int*)(smem + 12544);            // 4096 B, packed lo16 v / hi16 n
    int* tsum = (int*)(smem + 16640);         // 1024 B
    float* lval_v = (float*)(smem + 17664);   // 1024 B
    int* lidx_v = (int*)(smem + 18688);       // 1024 B
    float* lval_n = (float*)(smem + 19712);   // 1024 B
    int* lidx_n = (int*)(smem + 20736);       // 1024 B
    float* wred = (float*)(smem + 21760);     // 64 B  [wave][4]
    int* sc = (int*)(smem + 21824);           // 6 ints: cntv cntn bsv abv bsn abn

    for (int n = tid; n < NN; n += 256) { rv[n] = rowv[b * NN + n]; rn[n] = rown_[b * NN + n]; }
    __syncthreads();
    float mnv = 1e30f, mxv = -1e30f, mnn = 1e30f, mxn = -1e30f;
    for (int n = tid; n < NN; n += 256) {
        float v = rv[n]; mnv = fminf(mnv, v); mxv = fmaxf(mxv, v);
        float u = rn[n]; mnn = fminf(mnn, u); mxn = fmaxf(mxn, u);
    }
    #pragma unroll
    for (int off = 32; off >= 1; off >>= 1) {
        mnv = fminf(mnv, __shfl_xor(mnv, off));
        mxv = fmaxf(mxv, __shfl_xor(mxv, off));
        mnn = fminf(mnn, __shfl_xor(mnn, off));
        mxn = fmaxf(mxn, __shfl_xor(mxn, off));
    }
    if ((tid & 63) == 0) {
        int wid = tid >> 6;
        wred[wid * 4 + 0] = mnv; wred[wid * 4 + 1] = mxv;
        wred[wid * 4 + 2] = mnn; wred[wid * 4 + 3] = mxn;
    }
    if (tid == 0) { sc[0] = 0; sc[1] = 0; }
    __syncthreads();
    mnv = fminf(fminf(wred[0], wred[4]), fminf(wred[8], wred[12]));
    mxv = fmaxf(fmaxf(wred[1], wred[5]), fmaxf(wred[9], wred[13]));
    mnn = fminf(fminf(wred[2], wred[6]), fminf(wred[10], wred[14]));
    mxn = fmaxf(fmaxf(wred[3], wred[7]), fmaxf(wred[11], wred[15]));
    float iv = 1.f / (mxv - mnv), inn = 1.f / (mxn - mnn);

    for (int n = tid; n < NN; n += 256) {
        rv[n] = (rv[n] - mnv) * iv;
        rn[n] = (rn[n] - mnn) * inn;
    }
    for (int i = tid; i < 1024; i += 256) h[i] = 0;
    __syncthreads();
    for (int n = tid; n < NN; n += 256) {
        atomicAdd(&h[binof(rv[n])], 1);
        atomicAdd(&h[binof(rn[n])], 1 << 16);
    }
    __syncthreads();

    int h0 = h[4 * tid], h1 = h[4 * tid + 1], h2 = h[4 * tid + 2], h3 = h[4 * tid + 3];
    tsum[tid] = h0 + h1 + h2 + h3;      // packed fieldwise sum (<=1568 per field)
    __syncthreads();
    for (int off = 1; off < 256; off <<= 1) {
        int add = (tid + off < 256) ? tsum[tid + off] : 0;
        __syncthreads();
        tsum[tid] += add;
        __syncthreads();
    }
    {
        int scur = tsum[tid];           // packed S(4t)
        int hk[4] = {h0, h1, h2, h3};
        #pragma unroll
        for (int k = 0; k < 4; ++k) {
            int snext = scur - hk[k];   // fieldwise, borrow-free
            int scv = scur & 0xffff, ncv = snext & 0xffff;
            int sh = scur >> 16, nh = snext >> 16;
            if (scv >= NTOK && ncv < NTOK) { sc[2] = 4 * tid + k; sc[3] = ncv; }
            if (sh >= NTOK && nh < NTOK) { sc[4] = 4 * tid + k; sc[5] = nh; }
            scur = snext;
        }
    }
    __syncthreads();
    int bsv = sc[2], abv = sc[3], bsn = sc[4], abn = sc[5];

    for (int n = tid; n < NN; n += 256) {
        float v = rv[n]; int bv = binof(v);
        if (bv < bsv) rv[n] = 0.f;
        else if (bv == bsv) {
            int s = atomicAdd(&sc[0], 1);
            if (s < BCAP) { lval_v[s] = v; lidx_v[s] = n; }
        }
        float u = rn[n]; int bu = binof(u);
        if (bu < bsn) rn[n] = 0.f;
        else if (bu == bsn) {
            int s = atomicAdd(&sc[1], 1);
            if (s < BCAP) { lval_n[s] = u; lidx_n[s] = n; }
        }
    }
    __syncthreads();
    int Lv = sc[0] < BCAP ? sc[0] : BCAP;
    int Ln = sc[1] < BCAP ? sc[1] : BCAP;
    for (int i = tid; i < Lv; i += 256) {
        float vi = lval_v[i]; int ni = lidx_v[i]; int r = 0;
        for (int j = 0; j < Lv; ++j) {
            float vj = lval_v[j]; int nj = lidx_v[j];
            r += (vj > vi || (vj == vi && nj < ni)) ? 1 : 0;
        }
        rv[ni] = (r < NTOK - abv) ? vi : 0.f;
    }
    for (int i = tid; i < Ln; i += 256) {
        float vi = lval_n[i]; int ni = lidx_n[i]; int r = 0;
        for (int j = 0; j < Ln; ++j) {
            float vj = lval_n[j]; int nj = lidx_n[j];
            r += (vj > vi || (vj == vi && nj < ni)) ? 1 : 0;
        }
        rn[ni] = (r < NTOK - abn) ? vi : 0.f;
    }
    __syncthreads();
    for (int n = tid; n < NN; n += 256) cam[b * NN + n] = fmaxf(rv[n], rn[n]);
}

// ---------------- K5: MFMA implicit-GEMM conv + fused relu/score + cam ------
// R6-verified GEMM core (B staged in LDS, xor-swizzle, XCD remap, slot
// stores). Blocks 0..63 run the cam selection (hides under the GEMM);
// blocks 64..3199 are the GEMM (gid = bid-64; 64%8==0 keeps XCD map).
__global__ __launch_bounds__(256, 3) void k_gemm(
        const __hip_bfloat16* __restrict__ xp, const __hip_bfloat16* __restrict__ wb,
        const float* __restrict__ convb, const float* __restrict__ scorew,
        float* __restrict__ pl, const float* __restrict__ rowv,
        const float* __restrict__ rown_, float* __restrict__ cam) {
    __shared__ char smem[32768];
    int tid = threadIdx.x;
    int bid = blockIdx.x;        // 0..3199
    if (bid < 64) { cam_block(bid, tid, smem, rowv, rown_, cam); return; }
    char* As = smem;             // [row 0..127][seg 0..7] bf16x8, swizzled
    char* Bs = smem + 16384;     // [d'  0..127][seg 0..7]
    int gid = bid - 64;          // 0..3135
    int xcd = gid & 7;
    int local = gid >> 3;        // 0..391
    int mtile = xcd * 98 + (local >> 2);
    int nblk = local & 3;
    int m0 = mtile * 128;
    int n0 = nblk * 128;
    int lane = tid & 63, wv = tid >> 6;
    int wm = wv >> 1, wn = wv & 1;
    int ln = lane & 15, qd = lane >> 4;

    int rrow = tid >> 3;
    int segst = ((tid & 7) ^ (rrow & 7)) * 8;     // element offset in row
    int bt_[4], hh_[4], ww_[4];
    const __hip_bfloat16* bptr[4];
    #pragma unroll
    for (int j = 0; j < 4; ++j) {
        int m = m0 + j * 32 + rrow;
        int bt = m / HW, q = m - bt * HW;
        bt_[j] = bt; hh_[j] = q / WW; ww_[j] = q - (q / WW) * WW;
        bptr[j] = wb + (size_t)(n0 + j * 32 + rrow) * 256 + segst;
    }

    int swz = ln & 7;
    int offk[2] = {((0 + qd) ^ swz) * 16, ((4 + qd) ^ swz) * 16};

    f32x4 acc[4][4];
    #pragma unroll
    for (int i = 0; i < 4; ++i)
        #pragma unroll
        for (int j = 0; j < 4; ++j) acc[i][j] = (f32x4){0.f, 0.f, 0.f, 0.f};

    for (int kk = 0; kk < 9; ++kk) {
        int kh = kk / 3, kw = kk - (kk / 3) * 3;
        const __hip_bfloat16* aptr[4];
        #pragma unroll
        for (int j = 0; j < 4; ++j)
            aptr[j] = xp + ((size_t)bt_[j] * 81 + (hh_[j] + kh) * 9 + (ww_[j] + kw)) * 256 + segst;
        const size_t boff = (size_t)kk * (DD * 256);
        #pragma unroll
        for (int c0 = 0; c0 < 256; c0 += 64) {
            __syncthreads();
            #pragma unroll
            for (int j = 0; j < 4; ++j) {
                GLDS(aptr[j] + c0, As + j * 4096 + tid * 16);
                GLDS(bptr[j] + boff + c0, Bs + j * 4096 + tid * 16);
            }
            __syncthreads();
            #pragma unroll
            for (int k2 = 0; k2 < 2; ++k2) {
                bf16x8 af[4], bfr[4];
                #pragma unroll
                for (int i = 0; i < 4; ++i)
                    af[i] = *(const bf16x8*)(As + (wm * 64 + i * 16 + ln) * 128 + offk[k2]);
                #pragma unroll
                for (int j = 0; j < 4; ++j)
                    bfr[j] = *(const bf16x8*)(Bs + (wn * 64 + j * 16 + ln) * 128 + offk[k2]);
                #pragma unroll
                for (int i = 0; i < 4; ++i)
                    #pragma unroll
                    for (int j = 0; j < 4; ++j)
                        acc[i][j] = __builtin_amdgcn_mfma_f32_16x16x32_bf16(af[i], bfr[j], acc[i][j], 0, 0, 0);
            }
        }
    }

    float swr[4], cbr[4];
    #pragma unroll
    for (int j = 0; j < 4; ++j) {
        int n = n0 + wn * 64 + j * 16 + ln;
        swr[j] = scorew[n];
        cbr[j] = convb[n];
    }
    float* dst = pl + (size_t)(nblk * 2 + wn) * TOTAL;
    #pragma unroll
    for (int i = 0; i < 4; ++i) {
        #pragma unroll
        for (int r = 0; r < 4; ++r) {
            float v = 0.f;
            #pragma unroll
            for (int j = 0; j < 4; ++j) {
                float h1 = acc[i][j][r] + cbr[j];
                h1 = h1 > 0.f ? h1 : 0.f;
                v = fmaf(swr[j], h1, v);
            }
            v += __shfl_xor(v, 1);
            v += __shfl_xor(v, 2);
            v += __shfl_xor(v, 4);
            v += __shfl_xor(v, 8);
            if (ln == 0)
                dst[m0 + wm * 64 + i * 16 + qd * 4 + r] = v;
        }
    }
}

// ---------------- K6: slot-sum + BCE + grid reduction (last block) ----------
__global__ __launch_bounds__(256) void k_bce(
        const float* __restrict__ pl, const float* __restrict__ cam,
        const float* __restrict__ sb, float* __restrict__ part,
        int* __restrict__ counter, float* __restrict__ out) {
    __shared__ float sbuf[256];
    __shared__ int isLast;
    int tid = threadIdx.x;
    int m = blockIdx.x * 256 + tid;
    float l = sb[0];
    #pragma unroll
    for (int s = 0; s < 8; ++s) l += pl[(size_t)s * TOTAL + m];
    float y = cam[m];
    float v = fmaxf(l, 0.f) - l * y + log1pf(expf(-fabsf(l)));
    sbuf[tid] = v; __syncthreads();
    for (int k = 128; k > 0; k >>= 1) {
        if (tid < k) sbuf[tid] += sbuf[tid + k];
        __syncthreads();
    }
    if (tid == 0) {
        part[blockIdx.x] = sbuf[0];
        __threadfence();
        int d = atomicAdd(counter, 1);
        isLast = (d == 391);
    }
    __syncthreads();
    if (isLast) {
        float s = 0.f;
        for (int i = tid; i < 392; i += 256) s += part[i];
        sbuf[tid] = s; __syncthreads();
        for (int k = 128; k > 0; k >>= 1) {
            if (tid < k) sbuf[tid] += sbuf[tid + k];
            __syncthreads();
        }
        if (tid == 0) out[0] = sbuf[0] * (1.0f / (float)TOTAL);
    }
}

extern "C" void kernel_launch(void* const* d_in, const int* in_sizes, int n_in,
                              void* d_out, int out_size, void* d_ws, size_t ws_size,
                              hipStream_t stream) {
    const float* x   = (const float*)d_in[0];
    const float* pv  = (const float*)d_in[1];
    const float* pn  = (const float*)d_in[2];
    const float* wpv = (const float*)d_in[3];
    const float* wpn = (const float*)d_in[4];
    const float* cw  = (const float*)d_in[5];
    const float* cb  = (const float*)d_in[6];
    const float* sw  = (const float*)d_in[7];
    const float* sb  = (const float*)d_in[8];

    char* w8 = (char*)d_ws;
    __hip_bfloat16* xp  = (__hip_bfloat16*)w8;                  // 84,934,656 B
    __hip_bfloat16* wb  = (__hip_bfloat16*)(w8 + 84934656);     //  2,359,296 B
    float* pl      = (float*)(w8 + 87293952);                   //  3,211,264 B
    float* rowv    = (float*)(w8 + 90505216);                   //    401,408 B
    float* rown_   = (float*)(w8 + 90906624);                   //    401,408 B
    float* cam     = (float*)(w8 + 91308032);                   //    401,408 B
    float* part    = (float*)(w8 + 91709440);                   //      1,568 B
    int*   counter = (int*)(w8 + 91711008);                     //          4 B

    k_xp<<<2048, 256, 0, stream>>>(x, xp, pv, pn, wpv, wpn, cw, wb,
                                   rowv, rown_, counter);
    k_gemm<<<64 + 3136, 256, 0, stream>>>(xp, wb, cb, sw, pl, rowv, rown_, cam);
    k_bce<<<392, 256, 0, stream>>>(pl, cam, sb, part, counter, (float*)d_out);
}